// Round 1
// baseline (591.658 us; speedup 1.0000x reference)
//
#include <hip/hip_runtime.h>
#include <hip/hip_bf16.h>
#include <stdint.h>
#include <stddef.h>

#define HIDDEN 4096
#define BATCH  4096
#define RANK   4

typedef _Float16 f16;
typedef __attribute__((ext_vector_type(8))) _Float16 half8;
typedef __attribute__((ext_vector_type(4))) float f32x4;
typedef __attribute__((ext_vector_type(8))) unsigned short ushort8;

// global->LDS async copy, 16B per lane. LDS dest is wave-uniform base + lane*16.
#define ASYNC_COPY16(g, l)                                                     \
  __builtin_amdgcn_global_load_lds(                                            \
      (__attribute__((address_space(1))) void*)(g),                            \
      (__attribute__((address_space(3))) void*)(l), 16, 0, 0)

// ---------------------------------------------------------------------------
// x (f32) -> f16, 8 elems/thread
__global__ void cast_f16_kernel(const float* __restrict__ src, f16* __restrict__ dst) {
  size_t i = ((size_t)blockIdx.x * blockDim.x + threadIdx.x) * 8;
  float4 v0 = *(const float4*)(src + i);
  float4 v1 = *(const float4*)(src + i + 4);
  union { f16 h[8]; ushort8 v; } u;
  u.h[0] = (f16)v0.x; u.h[1] = (f16)v0.y; u.h[2] = (f16)v0.z; u.h[3] = (f16)v0.w;
  u.h[4] = (f16)v1.x; u.h[5] = (f16)v1.y; u.h[6] = (f16)v1.z; u.h[7] = (f16)v1.w;
  *(ushort8*)(dst + i) = u.v;
}

// ---------------------------------------------------------------------------
// b_mat [K][N] f32 -> Bt [N][K] f16, 64x64 LDS tile transpose
__global__ void transpose_cast_kernel(const float* __restrict__ B, f16* __restrict__ Bt) {
  __shared__ f16 tile[64][80];  // stride 80 elems = 160 B: 16B-aligned rows
  const int t = threadIdx.x;
  const int bx = blockIdx.x;  // n tile
  const int by = blockIdx.y;  // k tile
  const int tx = t & 15, ty = t >> 4;
  #pragma unroll
  for (int i = 0; i < 4; i++) {
    int row = ty + i * 16;  // k local
    float4 v = *(const float4*)(B + (size_t)(by * 64 + row) * HIDDEN + bx * 64 + tx * 4);
    tile[tx * 4 + 0][row] = (f16)v.x;
    tile[tx * 4 + 1][row] = (f16)v.y;
    tile[tx * 4 + 2][row] = (f16)v.z;
    tile[tx * 4 + 3][row] = (f16)v.w;
  }
  __syncthreads();
  const int wx = t & 7, wy = t >> 3;
  #pragma unroll
  for (int i = 0; i < 2; i++) {
    int n = wy + i * 32;
    ushort8 v = *(ushort8*)&tile[n][wx * 8];
    *(ushort8*)(Bt + (size_t)(bx * 64 + n) * HIDDEN + by * 64 + wx * 8) = v;
  }
}

// ---------------------------------------------------------------------------
// hq[b][r] = sum_k h[b][k] * q[k][r]   (f32 exact-ish)
__global__ void hq_kernel(const float* __restrict__ h, const float* __restrict__ q,
                          float* __restrict__ hq) {
  const int b = blockIdx.x;
  const float* hrow = h + (size_t)b * HIDDEN;
  float a0 = 0.f, a1 = 0.f, a2 = 0.f, a3 = 0.f;
  for (int k = threadIdx.x; k < HIDDEN; k += 256) {
    float hv = hrow[k];
    float4 qv = *(const float4*)(q + (size_t)k * RANK);
    a0 += hv * qv.x; a1 += hv * qv.y; a2 += hv * qv.z; a3 += hv * qv.w;
  }
  #pragma unroll
  for (int off = 32; off; off >>= 1) {
    a0 += __shfl_down(a0, off, 64);
    a1 += __shfl_down(a1, off, 64);
    a2 += __shfl_down(a2, off, 64);
    a3 += __shfl_down(a3, off, 64);
  }
  __shared__ float red[4][4];
  const int wave = threadIdx.x >> 6, lane = threadIdx.x & 63;
  if (lane == 0) { red[wave][0] = a0; red[wave][1] = a1; red[wave][2] = a2; red[wave][3] = a3; }
  __syncthreads();
  if (threadIdx.x < 4) {
    float s = red[0][threadIdx.x] + red[1][threadIdx.x] + red[2][threadIdx.x] + red[3][threadIdx.x];
    hq[(size_t)b * RANK + threadIdx.x] = s;
  }
}

// ---------------------------------------------------------------------------
// Main GEMM: out = Xb(f16) @ Bt(f16)^T + h*(1+a) + hq @ p^T, f32 out.
// m97 structure: 128x128x32 tile, 4 waves, each wave 4x4 MFMA 16x16x32 tiles.
#define BM 128
#define BN 128
#define BK 32

__global__ void gemm_fused_kernel(const f16* __restrict__ Xb, const f16* __restrict__ Bt,
                                  const float* __restrict__ h, const float* __restrict__ a_diag,
                                  const float* __restrict__ p_vec, const float* __restrict__ hq,
                                  float* __restrict__ out) {
  __shared__ f16 As[BM * BK];  // [m][k], 8 KB
  __shared__ f16 Bs[BN * BK];  // [n][k], 8 KB
  const int tid = threadIdx.x;
  const int bm = blockIdx.x, bn = blockIdx.y;
  const int wave = tid >> 6, lane = tid & 63;
  const int wm = wave & 1, wn = wave >> 1;

  // staging: thread t covers tile row t/4 (and +64), k-segment (t&3)*8
  const f16* ag = Xb + (size_t)(bm * BM + (tid >> 2)) * HIDDEN + (tid & 3) * 8;
  const f16* bg = Bt + (size_t)(bn * BN + (tid >> 2)) * HIDDEN + (tid & 3) * 8;
  char* as_base = (char*)As + wave * 1024;  // lane*16 added by HW
  char* bs_base = (char*)Bs + wave * 1024;

  f32x4 acc[4][4];
  #pragma unroll
  for (int i = 0; i < 4; i++)
    #pragma unroll
    for (int j = 0; j < 4; j++)
      acc[i][j] = (f32x4){0.f, 0.f, 0.f, 0.f};

  const int fm = lane & 15;        // m/n index within 16x16 frag
  const int fk = (lane >> 4) * 8;  // k offset within 32

  for (int k0 = 0; k0 < HIDDEN; k0 += BK) {
    ASYNC_COPY16(ag, as_base);
    ASYNC_COPY16(ag + (size_t)64 * HIDDEN, as_base + 4096);
    ASYNC_COPY16(bg, bs_base);
    ASYNC_COPY16(bg + (size_t)64 * HIDDEN, bs_base + 4096);
    ag += BK; bg += BK;
    __syncthreads();  // compiler drains vmcnt before s_barrier

    half8 af[4], bfr[4];
    #pragma unroll
    for (int i = 0; i < 4; i++)
      af[i] = *(const half8*)(As + (wm * 64 + i * 16 + fm) * BK + fk);
    #pragma unroll
    for (int j = 0; j < 4; j++)
      bfr[j] = *(const half8*)(Bs + (wn * 64 + j * 16 + fm) * BK + fk);
    #pragma unroll
    for (int i = 0; i < 4; i++)
      #pragma unroll
      for (int j = 0; j < 4; j++)
        acc[i][j] = __builtin_amdgcn_mfma_f32_16x16x32_f16(af[i], bfr[j], acc[i][j], 0, 0, 0);
    __syncthreads();
  }

  // epilogue: C/D layout col = lane&15, row = (lane>>4)*4 + reg  [m89/m91]
  #pragma unroll
  for (int j = 0; j < 4; j++) {
    const int gn = bn * BN + wn * 64 + j * 16 + (lane & 15);
    const float ad = 1.0f + a_diag[gn];
    const float4 pv = *(const float4*)(p_vec + (size_t)gn * RANK);
    #pragma unroll
    for (int i = 0; i < 4; i++) {
      const int rb = bm * BM + wm * 64 + i * 16 + (lane >> 4) * 4;
      #pragma unroll
      for (int r = 0; r < 4; r++) {
        const size_t gb = (size_t)(rb + r);
        const float4 hv = *(const float4*)(hq + gb * RANK);
        const size_t idx = gb * HIDDEN + gn;
        out[idx] = acc[i][j][r] + h[idx] * ad +
                   hv.x * pv.x + hv.y * pv.y + hv.z * pv.z + hv.w * pv.w;
      }
    }
  }
}

// ---------------------------------------------------------------------------
// Fallback (ws too small): straight f32 LDS-tiled GEMM + same epilogue.
__global__ void gemm_f32_fallback_kernel(const float* __restrict__ x, const float* __restrict__ bmat,
                                         const float* __restrict__ h, const float* __restrict__ a_diag,
                                         const float* __restrict__ p_vec, const float* __restrict__ hq,
                                         float* __restrict__ out) {
  __shared__ float As[16][64];
  __shared__ float Bs[16][68];
  const int t = threadIdx.x;
  const int bx = blockIdx.x, by = blockIdx.y;  // bx: n tile, by: m tile
  const int tm = t & 15, tn = t >> 4;
  float acc[4][4] = {{0.f}};
  for (int k0 = 0; k0 < HIDDEN; k0 += 16) {
    #pragma unroll
    for (int l = 0; l < 4; l++) {
      int idx = t + l * 256;
      int r = idx >> 4, k = idx & 15;
      As[k][r] = x[(size_t)(by * 64 + r) * HIDDEN + k0 + k];
      int kb = idx >> 6, nb = idx & 63;
      Bs[kb][nb] = bmat[(size_t)(k0 + kb) * HIDDEN + bx * 64 + nb];
    }
    __syncthreads();
    #pragma unroll
    for (int k = 0; k < 16; k++) {
      float av[4], bv[4];
      #pragma unroll
      for (int ii = 0; ii < 4; ii++) av[ii] = As[k][tm * 4 + ii];
      #pragma unroll
      for (int jj = 0; jj < 4; jj++) bv[jj] = Bs[k][tn * 4 + jj];
      #pragma unroll
      for (int ii = 0; ii < 4; ii++)
        #pragma unroll
        for (int jj = 0; jj < 4; jj++)
          acc[ii][jj] += av[ii] * bv[jj];
    }
    __syncthreads();
  }
  #pragma unroll
  for (int jj = 0; jj < 4; jj++) {
    int gn = bx * 64 + tn * 4 + jj;
    float ad = 1.0f + a_diag[gn];
    float4 pv = *(const float4*)(p_vec + (size_t)gn * RANK);
    #pragma unroll
    for (int ii = 0; ii < 4; ii++) {
      size_t gb = (size_t)(by * 64 + tm * 4 + ii);
      float4 hv = *(const float4*)(hq + gb * RANK);
      size_t idx = gb * HIDDEN + gn;
      out[idx] = acc[ii][jj] + h[idx] * ad +
                 hv.x * pv.x + hv.y * pv.y + hv.z * pv.z + hv.w * pv.w;
    }
  }
}

// ---------------------------------------------------------------------------
extern "C" void kernel_launch(void* const* d_in, const int* in_sizes, int n_in,
                              void* d_out, int out_size, void* d_ws, size_t ws_size,
                              hipStream_t stream) {
  const float* h      = (const float*)d_in[0];
  const float* x      = (const float*)d_in[1];
  const float* a_diag = (const float*)d_in[2];
  const float* p_vec  = (const float*)d_in[3];
  const float* q_vec  = (const float*)d_in[4];
  const float* b_mat  = (const float*)d_in[5];
  float* out = (float*)d_out;

  const size_t nElem = (size_t)BATCH * HIDDEN;
  const size_t hq_bytes = (size_t)BATCH * RANK * sizeof(float);       // 64 KB
  const size_t need = hq_bytes + 2 * nElem * sizeof(f16);             // + Xb + Bt

  float* hq = (float*)d_ws;
  hq_kernel<<<BATCH, 256, 0, stream>>>(h, q_vec, hq);

  if (ws_size >= need) {
    f16* Xb = (f16*)((char*)d_ws + hq_bytes);
    f16* Bt = Xb + nElem;
    cast_f16_kernel<<<nElem / 2048, 256, 0, stream>>>(x, Xb);
    transpose_cast_kernel<<<dim3(HIDDEN / 64, HIDDEN / 64), 256, 0, stream>>>(b_mat, Bt);
    gemm_fused_kernel<<<dim3(BATCH / BM, HIDDEN / BN), 256, 0, stream>>>(
        Xb, Bt, h, a_diag, p_vec, hq, out);
  } else {
    gemm_f32_fallback_kernel<<<dim3(HIDDEN / 64, BATCH / 64), 256, 0, stream>>>(
        x, b_mat, h, a_diag, p_vec, hq, out);
  }
}

// Round 2
// 381.052 us; speedup vs baseline: 1.5527x; 1.5527x over previous
//
#include <hip/hip_runtime.h>
#include <hip/hip_bf16.h>
#include <stdint.h>
#include <stddef.h>

#define HIDDEN 4096
#define BATCH  4096
#define RANK   4

typedef _Float16 f16;
typedef __attribute__((ext_vector_type(8))) _Float16 half8;
typedef __attribute__((ext_vector_type(4))) float f32x4;
typedef __attribute__((ext_vector_type(8))) unsigned short ushort8;

// global->LDS async copy, 16B per lane. LDS dest is wave-uniform base + lane*16.
#define ASYNC_COPY16(g, l)                                                     \
  __builtin_amdgcn_global_load_lds(                                            \
      (__attribute__((address_space(1))) void*)(g),                            \
      (__attribute__((address_space(3))) void*)(l), 16, 0, 0)

// ---------------------------------------------------------------------------
// x (f32) -> f16, 8 elems/thread
__global__ void cast_f16_kernel(const float* __restrict__ src, f16* __restrict__ dst) {
  size_t i = ((size_t)blockIdx.x * blockDim.x + threadIdx.x) * 8;
  float4 v0 = *(const float4*)(src + i);
  float4 v1 = *(const float4*)(src + i + 4);
  union { f16 h[8]; ushort8 v; } u;
  u.h[0] = (f16)v0.x; u.h[1] = (f16)v0.y; u.h[2] = (f16)v0.z; u.h[3] = (f16)v0.w;
  u.h[4] = (f16)v1.x; u.h[5] = (f16)v1.y; u.h[6] = (f16)v1.z; u.h[7] = (f16)v1.w;
  *(ushort8*)(dst + i) = u.v;
}

// ---------------------------------------------------------------------------
// b_mat [K][N] f32 -> Bt [N][K] f16, 64x64 LDS tile transpose
__global__ void transpose_cast_kernel(const float* __restrict__ B, f16* __restrict__ Bt) {
  __shared__ f16 tile[64][80];  // stride 80 elems = 160 B: 16B-aligned rows
  const int t = threadIdx.x;
  const int bx = blockIdx.x;  // n tile
  const int by = blockIdx.y;  // k tile
  const int tx = t & 15, ty = t >> 4;
  #pragma unroll
  for (int i = 0; i < 4; i++) {
    int row = ty + i * 16;  // k local
    float4 v = *(const float4*)(B + (size_t)(by * 64 + row) * HIDDEN + bx * 64 + tx * 4);
    tile[tx * 4 + 0][row] = (f16)v.x;
    tile[tx * 4 + 1][row] = (f16)v.y;
    tile[tx * 4 + 2][row] = (f16)v.z;
    tile[tx * 4 + 3][row] = (f16)v.w;
  }
  __syncthreads();
  const int wx = t & 7, wy = t >> 3;
  #pragma unroll
  for (int i = 0; i < 2; i++) {
    int n = wy + i * 32;
    ushort8 v = *(ushort8*)&tile[n][wx * 8];
    *(ushort8*)(Bt + (size_t)(bx * 64 + n) * HIDDEN + by * 64 + wx * 8) = v;
  }
}

// ---------------------------------------------------------------------------
// hq[b][r] = sum_k h[b][k] * q[k][r]   (f32)
__global__ void hq_kernel(const float* __restrict__ h, const float* __restrict__ q,
                          float* __restrict__ hq) {
  const int b = blockIdx.x;
  const float* hrow = h + (size_t)b * HIDDEN;
  float a0 = 0.f, a1 = 0.f, a2 = 0.f, a3 = 0.f;
  for (int k = threadIdx.x; k < HIDDEN; k += 256) {
    float hv = hrow[k];
    float4 qv = *(const float4*)(q + (size_t)k * RANK);
    a0 += hv * qv.x; a1 += hv * qv.y; a2 += hv * qv.z; a3 += hv * qv.w;
  }
  #pragma unroll
  for (int off = 32; off; off >>= 1) {
    a0 += __shfl_down(a0, off, 64);
    a1 += __shfl_down(a1, off, 64);
    a2 += __shfl_down(a2, off, 64);
    a3 += __shfl_down(a3, off, 64);
  }
  __shared__ float red[4][4];
  const int wave = threadIdx.x >> 6, lane = threadIdx.x & 63;
  if (lane == 0) { red[wave][0] = a0; red[wave][1] = a1; red[wave][2] = a2; red[wave][3] = a3; }
  __syncthreads();
  if (threadIdx.x < 4) {
    float s = red[0][threadIdx.x] + red[1][threadIdx.x] + red[2][threadIdx.x] + red[3][threadIdx.x];
    hq[(size_t)b * RANK + threadIdx.x] = s;
  }
}

// ---------------------------------------------------------------------------
// Main GEMM: out = Xb(f16) @ Bt(f16)^T + h*(1+a) + hq @ p^T, f32 out.
// 128x128x64 tile, 4 waves, each wave 4x4 MFMA 16x16x32 tiles, 2 k-steps/iter.
// LDS layout [m][k] with XOR segment swizzle applied at the staging SOURCE
// (global_load_lds dest must stay lane-linear): LDS[m][s] holds global
// k-segment (s ^ (m&7)). Fragment reads then hit 8 distinct bank-bases per
// 16-lane phase -> 2-way (free) instead of 8-way conflicts.
#define BM 128
#define BN 128
#define BK 64

__global__ __launch_bounds__(256) void gemm_fused_kernel(
    const f16* __restrict__ Xb, const f16* __restrict__ Bt,
    const float* __restrict__ h, const float* __restrict__ a_diag,
    const float* __restrict__ p_vec, const float* __restrict__ hq,
    float* __restrict__ out) {
  __shared__ f16 As[BM * BK];  // 16 KB, row = 128 B = 8 segs x 16 B
  __shared__ f16 Bs[BN * BK];  // 16 KB
  const int tid = threadIdx.x;
  const int bm = blockIdx.x, bn = blockIdx.y;
  const int wave = tid >> 6, lane = tid & 63;
  const int wm = wave & 1, wn = wave >> 1;

  // staging: thread t covers LDS row (t>>3) + 32*o, stored segment (t&7);
  // its global source segment is XOR-swizzled by the row.
  const int srow = tid >> 3;                       // 0..31
  const int sseg = (tid & 7) ^ (srow & 7);         // swizzled global k-seg
  const f16* ag = Xb + (size_t)(bm * BM + srow) * HIDDEN + sseg * 8;
  const f16* bg = Bt + (size_t)(bn * BN + srow) * HIDDEN + sseg * 8;
  char* as_base = (char*)As + wave * 1024;         // + lane*16 added by HW
  char* bs_base = (char*)Bs + wave * 1024;
  const size_t rowblk = (size_t)32 * HIDDEN;       // 32-row advance (elems)

  f32x4 acc[4][4];
  #pragma unroll
  for (int i = 0; i < 4; i++)
    #pragma unroll
    for (int j = 0; j < 4; j++)
      acc[i][j] = (f32x4){0.f, 0.f, 0.f, 0.f};

  const int q = lane >> 4;    // 0..3: k-quad within 16x16x32 fragment
  const int fm = lane & 15;   // m/n index within fragment
  const int swz = lane & 7;   // = (fragment row) & 7 for all i (16,64 = 0 mod 8)

  for (int k0 = 0; k0 < HIDDEN; k0 += BK) {
    #pragma unroll
    for (int o = 0; o < 4; o++) {
      ASYNC_COPY16(ag + o * rowblk, as_base + o * 4096);
      ASYNC_COPY16(bg + o * rowblk, bs_base + o * 4096);
    }
    ag += BK; bg += BK;
    __syncthreads();  // drains vmcnt: staged tile visible

    #pragma unroll
    for (int kk = 0; kk < 2; kk++) {
      const int sa = ((kk << 2) | q) ^ swz;  // swizzled LDS segment
      half8 af[4], bf[4];
      #pragma unroll
      for (int i = 0; i < 4; i++)
        af[i] = *(const half8*)(As + (wm * 64 + i * 16 + fm) * BK + sa * 8);
      #pragma unroll
      for (int j = 0; j < 4; j++)
        bf[j] = *(const half8*)(Bs + (wn * 64 + j * 16 + fm) * BK + sa * 8);
      #pragma unroll
      for (int i = 0; i < 4; i++)
        #pragma unroll
        for (int j = 0; j < 4; j++)
          acc[i][j] = __builtin_amdgcn_mfma_f32_16x16x32_f16(af[i], bf[j], acc[i][j], 0, 0, 0);
    }
    __syncthreads();
  }

  // epilogue: C/D layout col = lane&15, row = (lane>>4)*4 + reg  [m89/m91]
  // j innermost: consecutive stores hit consecutive 64B segments of the same
  // rows -> full-line write combining; nontemporal avoids RFO + L2 pollution.
  float ad[4];
  float4 pv[4];
  #pragma unroll
  for (int j = 0; j < 4; j++) {
    const int gn = bn * BN + wn * 64 + j * 16 + fm;
    ad[j] = 1.0f + a_diag[gn];
    pv[j] = *(const float4*)(p_vec + (size_t)gn * RANK);
  }
  #pragma unroll
  for (int i = 0; i < 4; i++) {
    #pragma unroll
    for (int r = 0; r < 4; r++) {
      const size_t gb = (size_t)(bm * BM + wm * 64 + i * 16 + q * 4 + r);
      const float4 hv = *(const float4*)(hq + gb * RANK);
      const size_t rowoff = gb * HIDDEN + bn * BN + wn * 64 + fm;
      #pragma unroll
      for (int j = 0; j < 4; j++) {
        const size_t idx = rowoff + j * 16;
        const float hval = __builtin_nontemporal_load(&h[idx]);
        const float v = acc[i][j][r] + hval * ad[j] +
                        hv.x * pv[j].x + hv.y * pv[j].y + hv.z * pv[j].z + hv.w * pv[j].w;
        __builtin_nontemporal_store(v, &out[idx]);
      }
    }
  }
}

// ---------------------------------------------------------------------------
// Fallback (ws too small): straight f32 LDS-tiled GEMM + same epilogue.
__global__ void gemm_f32_fallback_kernel(const float* __restrict__ x, const float* __restrict__ bmat,
                                         const float* __restrict__ h, const float* __restrict__ a_diag,
                                         const float* __restrict__ p_vec, const float* __restrict__ hq,
                                         float* __restrict__ out) {
  __shared__ float As[16][64];
  __shared__ float Bs[16][68];
  const int t = threadIdx.x;
  const int bx = blockIdx.x, by = blockIdx.y;  // bx: n tile, by: m tile
  const int tm = t & 15, tn = t >> 4;
  float acc[4][4] = {{0.f}};
  for (int k0 = 0; k0 < HIDDEN; k0 += 16) {
    #pragma unroll
    for (int l = 0; l < 4; l++) {
      int idx = t + l * 256;
      int r = idx >> 4, k = idx & 15;
      As[k][r] = x[(size_t)(by * 64 + r) * HIDDEN + k0 + k];
      int kb = idx >> 6, nb = idx & 63;
      Bs[kb][nb] = bmat[(size_t)(k0 + kb) * HIDDEN + bx * 64 + nb];
    }
    __syncthreads();
    #pragma unroll
    for (int k = 0; k < 16; k++) {
      float av[4], bv[4];
      #pragma unroll
      for (int ii = 0; ii < 4; ii++) av[ii] = As[k][tm * 4 + ii];
      #pragma unroll
      for (int jj = 0; jj < 4; jj++) bv[jj] = Bs[k][tn * 4 + jj];
      #pragma unroll
      for (int ii = 0; ii < 4; ii++)
        #pragma unroll
        for (int jj = 0; jj < 4; jj++)
          acc[ii][jj] += av[ii] * bv[jj];
    }
    __syncthreads();
  }
  #pragma unroll
  for (int jj = 0; jj < 4; jj++) {
    int gn = bx * 64 + tn * 4 + jj;
    float ad = 1.0f + a_diag[gn];
    float4 pv = *(const float4*)(p_vec + (size_t)gn * RANK);
    #pragma unroll
    for (int ii = 0; ii < 4; ii++) {
      size_t gb = (size_t)(by * 64 + tm * 4 + ii);
      float4 hv = *(const float4*)(hq + gb * RANK);
      size_t idx = gb * HIDDEN + gn;
      out[idx] = acc[ii][jj] + h[idx] * ad +
                 hv.x * pv.x + hv.y * pv.y + hv.z * pv.z + hv.w * pv.w;
    }
  }
}

// ---------------------------------------------------------------------------
extern "C" void kernel_launch(void* const* d_in, const int* in_sizes, int n_in,
                              void* d_out, int out_size, void* d_ws, size_t ws_size,
                              hipStream_t stream) {
  const float* h      = (const float*)d_in[0];
  const float* x      = (const float*)d_in[1];
  const float* a_diag = (const float*)d_in[2];
  const float* p_vec  = (const float*)d_in[3];
  const float* q_vec  = (const float*)d_in[4];
  const float* b_mat  = (const float*)d_in[5];
  float* out = (float*)d_out;

  const size_t nElem = (size_t)BATCH * HIDDEN;
  const size_t hq_bytes = (size_t)BATCH * RANK * sizeof(float);       // 64 KB
  const size_t need = hq_bytes + 2 * nElem * sizeof(f16);             // + Xb + Bt

  float* hq = (float*)d_ws;
  hq_kernel<<<BATCH, 256, 0, stream>>>(h, q_vec, hq);

  if (ws_size >= need) {
    f16* Xb = (f16*)((char*)d_ws + hq_bytes);
    f16* Bt = Xb + nElem;
    cast_f16_kernel<<<nElem / 2048, 256, 0, stream>>>(x, Xb);
    transpose_cast_kernel<<<dim3(HIDDEN / 64, HIDDEN / 64), 256, 0, stream>>>(b_mat, Bt);
    gemm_fused_kernel<<<dim3(BATCH / BM, HIDDEN / BN), 256, 0, stream>>>(
        Xb, Bt, h, a_diag, p_vec, hq, out);
  } else {
    gemm_f32_fallback_kernel<<<dim3(HIDDEN / 64, BATCH / 64), 256, 0, stream>>>(
        x, b_mat, h, a_diag, p_vec, hq, out);
  }
}